// Round 1
// baseline (99.666 us; speedup 1.0000x reference)
//
#include <hip/hip_runtime.h>

// Chamfer loss: B=4, N=M=8192, D=3, fp32 in, scalar fp32 out.
// loss = mean_n min_m ||x_n-y_m||^2 + mean_m min_n ||...||^2 + lambda*bpp
//
// Strategy: VALU-bound pairwise pass. One fused kernel covers BOTH
// directions (1024 blocks total) so the 256 CUs stay busy. Each thread
// holds XR=8 source points in registers and streams a 256-point chunk of
// the other cloud through LDS (broadcast ds_reads, amortized over 8x the
// VALU work). Cross-chunk min via atomicMin on uint (float bits of
// non-negative fp32 are monotone under uint compare).

#define NPTS   8192
#define NB     4
#define NTHR   256
#define XR     8          // x points per thread -> x-tile = 2048
#define XTILES 4          // 8192 / 2048
#define YC     256        // y chunk size
#define YCHUNKS 32        // 8192 / 256

__global__ __launch_bounds__(NTHR) void init_min(unsigned int* mins, int n) {
    int i = blockIdx.x * blockDim.x + threadIdx.x;
    if (i < n) mins[i] = 0x7F800000u;   // +inf bits
}

__global__ __launch_bounds__(NTHR) void chamfer_pass(
        const float* __restrict__ X, const float* __restrict__ Y,
        unsigned int* __restrict__ minx, unsigned int* __restrict__ miny) {
    // grid = 1024: dir(2) x batch(4) x xtile(4) x ychunk(32)
    int bid    = blockIdx.x;
    int dir    = bid >> 9;
    int r      = bid & 511;
    int b      = r >> 7;
    int rem    = r & 127;
    int xtile  = rem >> 5;
    int ychunk = rem & 31;

    const float* src   = dir ? Y : X;     // cloud we take mins FOR
    const float* other = dir ? X : Y;     // cloud we min OVER
    unsigned int* outmin = dir ? miny : minx;

    __shared__ float ly[YC * 3];
    int t = threadIdx.x;

    // stage y-chunk into LDS (coalesced: 768 floats, 3 per thread)
    const float* ybase = other + ((size_t)b * NPTS + (size_t)ychunk * YC) * 3;
    for (int i = t; i < YC * 3; i += NTHR) ly[i] = ybase[i];
    __syncthreads();

    // load XR x-points into registers (stride-256 so global reads coalesce)
    float xx[XR], xy[XR], xz[XR], mn[XR];
    const float* xb = src + ((size_t)b * NPTS + (size_t)xtile * (NTHR * XR)) * 3;
#pragma unroll
    for (int k = 0; k < XR; k++) {
        int xi = k * NTHR + t;
        xx[k] = xb[xi * 3 + 0];
        xy[k] = xb[xi * 3 + 1];
        xz[k] = xb[xi * 3 + 2];
        mn[k] = 3.0e38f;
    }

#pragma unroll 4
    for (int j = 0; j < YC; j++) {
        float yx = ly[3 * j + 0];   // broadcast: all lanes same addr
        float yy = ly[3 * j + 1];
        float yz = ly[3 * j + 2];
#pragma unroll
        for (int k = 0; k < XR; k++) {
            float dx = xx[k] - yx;
            float dy = xy[k] - yy;
            float dz = xz[k] - yz;
            float d2 = dx * dx + dy * dy + dz * dz;  // mul + 2 fma
            mn[k] = fminf(mn[k], d2);
        }
    }

    unsigned int* om = outmin + (size_t)b * NPTS + (size_t)xtile * (NTHR * XR);
#pragma unroll
    for (int k = 0; k < XR; k++) {
        atomicMin(&om[k * NTHR + t], __float_as_uint(mn[k]));
    }
}

__global__ __launch_bounds__(1024) void reduce_k(
        const unsigned int* __restrict__ minx,
        const unsigned int* __restrict__ miny,
        const float* __restrict__ bpp, const float* __restrict__ lam,
        float* __restrict__ out) {
    __shared__ float s1[1024], s2[1024];
    int t = threadIdx.x;
    float sx = 0.f, sy = 0.f;
    for (int i = t; i < NB * NPTS; i += 1024) {
        sx += __uint_as_float(minx[i]);
        sy += __uint_as_float(miny[i]);
    }
    s1[t] = sx; s2[t] = sy;
    __syncthreads();
    for (int s = 512; s > 0; s >>= 1) {
        if (t < s) { s1[t] += s1[t + s]; s2[t] += s2[t + s]; }
        __syncthreads();
    }
    if (t == 0) {
        const float inv = 1.0f / (float)(NB * NPTS);
        out[0] = s1[0] * inv + s2[0] * inv + lam[0] * bpp[0];
    }
}

extern "C" void kernel_launch(void* const* d_in, const int* in_sizes, int n_in,
                              void* d_out, int out_size, void* d_ws, size_t ws_size,
                              hipStream_t stream) {
    const float* X   = (const float*)d_in[0];   // pc_pred  [4,8192,3]
    const float* Y   = (const float*)d_in[1];   // pc_target[4,8192,3]
    const float* bpp = (const float*)d_in[2];
    const float* lam = (const float*)d_in[3];
    float* out = (float*)d_out;

    unsigned int* minx = (unsigned int*)d_ws;          // 32768 uints
    unsigned int* miny = minx + NB * NPTS;             // 32768 uints

    int ntot = 2 * NB * NPTS;
    init_min<<<(ntot + NTHR - 1) / NTHR, NTHR, 0, stream>>>(minx, ntot);
    chamfer_pass<<<2 * NB * XTILES * YCHUNKS, NTHR, 0, stream>>>(X, Y, minx, miny);
    reduce_k<<<1, 1024, 0, stream>>>(minx, miny, bpp, lam, out);
}

// Round 2
// 66.980 us; speedup vs baseline: 1.4880x; 1.4880x over previous
//
#include <hip/hip_runtime.h>

// Chamfer loss: B=4, N=M=8192, D=3, fp32 in, scalar fp32 out.
// loss = mean_n min_m ||x_n-y_m||^2 + mean_m min_n ||...||^2 + lambda*bpp
//
// R1: 4 VALU ops/pair instead of 7. Use d2 = x2 + (y2 - 2 x.y); the x2
// term commutes with min_y, so the pass kernel only tracks
// m = min_y (y2 - 2 x.y) via 3 FMA + 1 min per pair, with the "other"
// cloud pre-transformed to (-2yx,-2yy,-2yz,y2) float4 in LDS
// (1 broadcast ds_read_b128 per y, amortized over XR=8 x-points).
// x2/y2 means are added in the reduce kernel. m can be negative ->
// signed-int atomicMin with monotone IEEE key (i<0 ? i^0x7FFFFFFF : i).

#define NPTS   8192
#define NB     4
#define NTHR   256
#define XR     8          // x points per thread -> x-tile = 2048
#define XTILES 4          // 8192 / 2048
#define YC     256        // y chunk size
#define YCHUNKS 32        // 8192 / 256

__device__ __forceinline__ int f2key(float f) {
    int i = __float_as_int(f);
    return i >= 0 ? i : (i ^ 0x7FFFFFFF);
}
__device__ __forceinline__ float key2f(int k) {
    return __int_as_float(k >= 0 ? k : (k ^ 0x7FFFFFFF));
}

__global__ __launch_bounds__(NTHR) void init_min(int* mins, int n) {
    int i = blockIdx.x * blockDim.x + threadIdx.x;
    if (i < n) mins[i] = 0x7F800000;   // key(+inf)
}

__global__ __launch_bounds__(NTHR) void chamfer_pass(
        const float* __restrict__ X, const float* __restrict__ Y,
        int* __restrict__ minx, int* __restrict__ miny) {
    // grid = 1024: dir(2) x batch(4) x xtile(4) x ychunk(32)
    int bid    = blockIdx.x;
    int dir    = bid >> 9;
    int r      = bid & 511;
    int b      = r >> 7;
    int rem    = r & 127;
    int xtile  = rem >> 5;
    int ychunk = rem & 31;

    const float* src   = dir ? Y : X;     // cloud we take mins FOR
    const float* other = dir ? X : Y;     // cloud we min OVER
    int* outmin        = dir ? miny : minx;

    __shared__ float4 ly4[YC];
    int t = threadIdx.x;

    // stage + transform y-chunk: thread t handles y point t of the chunk
    {
        const float* yb = other + ((size_t)b * NPTS + (size_t)ychunk * YC + t) * 3;
        float yx = yb[0], yy = yb[1], yz = yb[2];
        ly4[t] = make_float4(-2.0f * yx, -2.0f * yy, -2.0f * yz,
                             yx * yx + yy * yy + yz * yz);
    }
    __syncthreads();

    // load XR x-points into registers (stride-256 so global reads coalesce)
    float xx[XR], xy[XR], xz[XR], mn[XR];
    const float* xb = src + ((size_t)b * NPTS + (size_t)xtile * (NTHR * XR)) * 3;
#pragma unroll
    for (int k = 0; k < XR; k++) {
        int xi = k * NTHR + t;
        xx[k] = xb[xi * 3 + 0];
        xy[k] = xb[xi * 3 + 1];
        xz[k] = xb[xi * 3 + 2];
        mn[k] = 3.0e38f;
    }

#pragma unroll 4
    for (int j = 0; j < YC; j++) {
        float4 y = ly4[j];          // broadcast ds_read_b128
#pragma unroll
        for (int k = 0; k < XR; k++) {
            float d = __fmaf_rn(xx[k], y.x, y.w);   // y.w = y2, y.x = -2yx
            d = __fmaf_rn(xy[k], y.y, d);
            d = __fmaf_rn(xz[k], y.z, d);
            mn[k] = fminf(mn[k], d);
        }
    }

    int* om = outmin + (size_t)b * NPTS + (size_t)xtile * (NTHR * XR);
#pragma unroll
    for (int k = 0; k < XR; k++) {
        atomicMin(&om[k * NTHR + t], f2key(mn[k]));
    }
}

__global__ __launch_bounds__(1024) void reduce_k(
        const int* __restrict__ minx, const int* __restrict__ miny,
        const float* __restrict__ X, const float* __restrict__ Y,
        const float* __restrict__ bpp, const float* __restrict__ lam,
        float* __restrict__ out) {
    __shared__ float s1[1024], s2[1024];
    int t = threadIdx.x;
    float sx = 0.f, sy = 0.f;
    for (int i = t; i < NB * NPTS; i += 1024) {
        sx += key2f(minx[i]);
        sy += key2f(miny[i]);
    }
    // add sum of ||x||^2 over X (for x->y direction) and ||y||^2 over Y
    for (int i = t; i < NB * NPTS; i += 1024) {
        float a0 = X[i * 3 + 0], a1 = X[i * 3 + 1], a2 = X[i * 3 + 2];
        sx += a0 * a0 + a1 * a1 + a2 * a2;
        float c0 = Y[i * 3 + 0], c1 = Y[i * 3 + 1], c2 = Y[i * 3 + 2];
        sy += c0 * c0 + c1 * c1 + c2 * c2;
    }
    s1[t] = sx; s2[t] = sy;
    __syncthreads();
    for (int s = 512; s > 0; s >>= 1) {
        if (t < s) { s1[t] += s1[t + s]; s2[t] += s2[t + s]; }
        __syncthreads();
    }
    if (t == 0) {
        const float inv = 1.0f / (float)(NB * NPTS);
        out[0] = s1[0] * inv + s2[0] * inv + lam[0] * bpp[0];
    }
}

extern "C" void kernel_launch(void* const* d_in, const int* in_sizes, int n_in,
                              void* d_out, int out_size, void* d_ws, size_t ws_size,
                              hipStream_t stream) {
    const float* X   = (const float*)d_in[0];   // pc_pred  [4,8192,3]
    const float* Y   = (const float*)d_in[1];   // pc_target[4,8192,3]
    const float* bpp = (const float*)d_in[2];
    const float* lam = (const float*)d_in[3];
    float* out = (float*)d_out;

    int* minx = (int*)d_ws;                    // 32768 int keys
    int* miny = minx + NB * NPTS;              // 32768 int keys

    int ntot = 2 * NB * NPTS;
    init_min<<<(ntot + NTHR - 1) / NTHR, NTHR, 0, stream>>>(minx, ntot);
    chamfer_pass<<<2 * NB * XTILES * YCHUNKS, NTHR, 0, stream>>>(X, Y, minx, miny);
    reduce_k<<<1, 1024, 0, stream>>>(minx, miny, X, Y, bpp, lam, out);
}

// Round 3
// 66.427 us; speedup vs baseline: 1.5004x; 1.0083x over previous
//
#include <hip/hip_runtime.h>

// Chamfer loss: B=4, N=M=8192, D=3, fp32 in, scalar fp32 out.
// loss = mean_n min_m ||x_n-y_m||^2 + mean_m min_n ||...||^2 + lambda*bpp
//
// R2: d2 = x2 + (y2 - 2 x.y); pass kernel tracks m = min_y (y2 - 2x.y).
// Thread holds XR=8 x-points as (-2x) in regs; y streams through LDS as
// raw float4 (x,y,z,||y||^2) precomputed by a prep kernel. Inner loop
// processes y-pairs: 6 FMA + 1 v_min3 per 2 pairs = 3.5 VALU/pair, with
// explicit register double-buffering of the LDS reads (prefetch j+2/j+3
// while computing j/j+1) so ds_read latency (~120cy) is fully hidden.
// Cross-block min via signed-int atomicMin on monotone IEEE keys.

#define NPTS   8192
#define NB     4
#define NTHR   256
#define XR     8          // x points per thread -> x-tile = 2048
#define XTILES 4          // 8192 / 2048
#define YC     256        // y chunk size
#define YCHUNKS 32        // 8192 / 256
#define NPTOT  (NB * NPTS)          // 32768 points per cloud

__device__ __forceinline__ int f2key(float f) {
    int i = __float_as_int(f);
    return i >= 0 ? i : (i ^ 0x7FFFFFFF);
}
__device__ __forceinline__ float key2f(int k) {
    return __int_as_float(k >= 0 ? k : (k ^ 0x7FFFFFFF));
}

// prep: i in [0, 2*NPTOT): build float4 (x,y,z,n2) for both clouds and
// init the min-key arrays (same element count, folded in).
__global__ __launch_bounds__(NTHR) void prep(
        const float* __restrict__ X, const float* __restrict__ Y,
        float4* __restrict__ P4 /* [2*NPTOT]: X4 then Y4 */,
        int* __restrict__ mins /* [2*NPTOT]: minx then miny */) {
    int i = blockIdx.x * blockDim.x + threadIdx.x;
    if (i >= 2 * NPTOT) return;
    const float* src = (i < NPTOT) ? X : Y;
    int idx = i & (NPTOT - 1);
    float a = src[idx * 3 + 0], b = src[idx * 3 + 1], c = src[idx * 3 + 2];
    P4[i] = make_float4(a, b, c, __fmaf_rn(a, a, __fmaf_rn(b, b, c * c)));
    mins[i] = 0x7F800000;   // key(+inf)
}

__global__ __launch_bounds__(NTHR) void chamfer_pass(
        const float4* __restrict__ P4, int* __restrict__ mins) {
    // grid = 1024: dir(2) x batch(4) x xtile(4) x ychunk(32)
    int bid    = blockIdx.x;
    int dir    = bid >> 9;
    int r      = bid & 511;
    int b      = r >> 7;
    int rem    = r & 127;
    int xtile  = rem >> 5;
    int ychunk = rem & 31;

    const float4* src4   = P4 + (dir ? NPTOT : 0);      // mins FOR this cloud
    const float4* other4 = P4 + (dir ? 0 : NPTOT);      // min OVER this cloud
    int* outmin          = mins + (dir ? NPTOT : 0);

    __shared__ float4 ly4[YC + 8];    // +8 pad: prefetch overread
    int t = threadIdx.x;

    // stage y-chunk (pure float4 copy, coalesced)
    ly4[t] = other4[(size_t)b * NPTS + (size_t)ychunk * YC + t];
    __syncthreads();

    // XR x-points in registers, pre-scaled by -2
    float xx[XR], xy[XR], xz[XR], mn[XR];
    const float4* xb = src4 + (size_t)b * NPTS + (size_t)xtile * (NTHR * XR);
#pragma unroll
    for (int k = 0; k < XR; k++) {
        float4 v = xb[k * NTHR + t];
        xx[k] = -2.0f * v.x;
        xy[k] = -2.0f * v.y;
        xz[k] = -2.0f * v.z;
        mn[k] = 3.0e38f;
    }

    // y-pair loop with register double-buffer (prefetch distance 2)
    float4 ya = ly4[0], yb = ly4[1];
#pragma unroll 4
    for (int j = 0; j < YC; j += 2) {
        float4 yc = ly4[j + 2];
        float4 yd = ly4[j + 3];
#pragma unroll
        for (int k = 0; k < XR; k++) {
            float d0 = __fmaf_rn(xx[k], ya.x, ya.w);
            d0 = __fmaf_rn(xy[k], ya.y, d0);
            d0 = __fmaf_rn(xz[k], ya.z, d0);
            float d1 = __fmaf_rn(xx[k], yb.x, yb.w);
            d1 = __fmaf_rn(xy[k], yb.y, d1);
            d1 = __fmaf_rn(xz[k], yb.z, d1);
            mn[k] = fminf(fminf(d0, d1), mn[k]);   // -> v_min3_f32
        }
        ya = yc; yb = yd;
    }

    int* om = outmin + (size_t)b * NPTS + (size_t)xtile * (NTHR * XR);
#pragma unroll
    for (int k = 0; k < XR; k++) {
        atomicMin(&om[k * NTHR + t], f2key(mn[k]));
    }
}

__global__ __launch_bounds__(1024) void reduce_k(
        const int* __restrict__ mins, const float4* __restrict__ P4,
        const float* __restrict__ bpp, const float* __restrict__ lam,
        float* __restrict__ out) {
    __shared__ float s1[1024], s2[1024];
    int t = threadIdx.x;
    float sx = 0.f, sy = 0.f;
    for (int i = t; i < NPTOT; i += 1024) {
        sx += key2f(mins[i]) + P4[i].w;                    // min + ||x||^2
        sy += key2f(mins[NPTOT + i]) + P4[NPTOT + i].w;    // min + ||y||^2
    }
    s1[t] = sx; s2[t] = sy;
    __syncthreads();
    for (int s = 512; s > 0; s >>= 1) {
        if (t < s) { s1[t] += s1[t + s]; s2[t] += s2[t + s]; }
        __syncthreads();
    }
    if (t == 0) {
        const float inv = 1.0f / (float)NPTOT;
        out[0] = s1[0] * inv + s2[0] * inv + lam[0] * bpp[0];
    }
}

extern "C" void kernel_launch(void* const* d_in, const int* in_sizes, int n_in,
                              void* d_out, int out_size, void* d_ws, size_t ws_size,
                              hipStream_t stream) {
    const float* X   = (const float*)d_in[0];   // pc_pred  [4,8192,3]
    const float* Y   = (const float*)d_in[1];   // pc_target[4,8192,3]
    const float* bpp = (const float*)d_in[2];
    const float* lam = (const float*)d_in[3];
    float* out = (float*)d_out;

    int*    mins = (int*)d_ws;                         // 2*32768 keys (256 KB)
    float4* P4   = (float4*)((char*)d_ws + 2 * NPTOT * sizeof(int));  // 1 MB

    prep<<<(2 * NPTOT + NTHR - 1) / NTHR, NTHR, 0, stream>>>(X, Y, P4, mins);
    chamfer_pass<<<2 * NB * XTILES * YCHUNKS, NTHR, 0, stream>>>(P4, mins);
    reduce_k<<<1, 1024, 0, stream>>>(mins, P4, bpp, lam, out);
}

// Round 4
// 54.027 us; speedup vs baseline: 1.8447x; 1.2295x over previous
//
#include <hip/hip_runtime.h>

// Chamfer loss: B=4, N=M=8192, D=3, fp32 in, scalar fp32 out.
// loss = mean_n min_m ||x_n-y_m||^2 + mean_m min_n ||...||^2 + lambda*bpp
//
// R3: packed fp32. d2 = x2 + (y2 - 2 x.y); pass tracks m = min_y(y2-2x.y).
// y-points processed in PAIRS via v_pk_fma_f32 (VOP3P, 2 fp32 FMA/instr —
// this is where the 157.3 TF fp32 peak lives; scalar v_fma is half rate).
// Per 2 pairs: 3 pk_fma + 1 min3 = 2 issue slots/pair (was 3.5).
// y staged in LDS as SoA (lyx/lyy/lyz/lyw) so a float2 read gives
// (y_j, y_{j+1}); x splatted to both halves in regs (hoisted).
// Reduce split: 64-block partial sums + 1-wave finalize (single-block
// reduce was reading 768KB from one CU, ~15us).

typedef float v2f __attribute__((ext_vector_type(2)));

#define NPTS   8192
#define NB     4
#define NTHR   256
#define XR     8          // x points per thread -> x-tile = 2048
#define XTILES 4          // 8192 / 2048
#define YC     256        // y chunk size
#define YCHUNKS 32        // 8192 / 256
#define NPTOT  (NB * NPTS)          // 32768 points per cloud
#define RBLK   64         // reduce stage-1 blocks

__device__ __forceinline__ int f2key(float f) {
    int i = __float_as_int(f);
    return i >= 0 ? i : (i ^ 0x7FFFFFFF);
}
__device__ __forceinline__ float key2f(int k) {
    return __int_as_float(k >= 0 ? k : (k ^ 0x7FFFFFFF));
}

// prep: i in [0, 2*NPTOT): SoA (x,y,z,||p||^2) for both clouds + min init.
__global__ __launch_bounds__(NTHR) void prep(
        const float* __restrict__ X, const float* __restrict__ Y,
        float* __restrict__ Sx, float* __restrict__ Sy,
        float* __restrict__ Sz, float* __restrict__ Sw,
        int* __restrict__ mins) {
    int i = blockIdx.x * blockDim.x + threadIdx.x;
    if (i >= 2 * NPTOT) return;
    const float* src = (i < NPTOT) ? X : Y;
    int idx = i & (NPTOT - 1);
    float a = src[idx * 3 + 0], b = src[idx * 3 + 1], c = src[idx * 3 + 2];
    Sx[i] = a; Sy[i] = b; Sz[i] = c;
    Sw[i] = __fmaf_rn(a, a, __fmaf_rn(b, b, c * c));
    mins[i] = 0x7F800000;   // key(+inf)
}

__global__ __launch_bounds__(NTHR) void chamfer_pass(
        const float* __restrict__ Sx, const float* __restrict__ Sy,
        const float* __restrict__ Sz, const float* __restrict__ Sw,
        int* __restrict__ mins) {
    // grid = 1024: dir(2) x batch(4) x xtile(4) x ychunk(32)
    int bid    = blockIdx.x;
    int dir    = bid >> 9;
    int r      = bid & 511;
    int b      = r >> 7;
    int rem    = r & 127;
    int xtile  = rem >> 5;
    int ychunk = rem & 31;

    __shared__ __align__(16) float lyx[YC], lyy[YC], lyz[YC], lyw[YC];
    int t = threadIdx.x;

    // stage y-chunk as SoA (4 coalesced float reads, broadcast-friendly)
    {
        size_t ob = (size_t)(dir ? 0 : NPTOT) + (size_t)b * NPTS
                  + (size_t)ychunk * YC + t;
        lyx[t] = Sx[ob]; lyy[t] = Sy[ob]; lyz[t] = Sz[ob]; lyw[t] = Sw[ob];
    }
    __syncthreads();

    // XR x-points in registers, pre-scaled by -2, splatted to both halves
    v2f xx[XR], xy[XR], xz[XR];
    float mn[XR];
    size_t sb = (size_t)(dir ? NPTOT : 0) + (size_t)b * NPTS
              + (size_t)xtile * (NTHR * XR) + t;
#pragma unroll
    for (int k = 0; k < XR; k++) {
        size_t xi = sb + (size_t)k * NTHR;
        float a = -2.0f * Sx[xi];
        float bb = -2.0f * Sy[xi];
        float c = -2.0f * Sz[xi];
        xx[k] = (v2f){a, a};
        xy[k] = (v2f){bb, bb};
        xz[k] = (v2f){c, c};
        mn[k] = 3.0e38f;
    }

#pragma unroll 4
    for (int j = 0; j < YC; j += 2) {
        v2f yx = *(const v2f*)&lyx[j];   // broadcast ds_read_b64
        v2f yy = *(const v2f*)&lyy[j];
        v2f yz = *(const v2f*)&lyz[j];
        v2f yw = *(const v2f*)&lyw[j];
#pragma unroll
        for (int k = 0; k < XR; k++) {
            v2f d = __builtin_elementwise_fma(xx[k], yx, yw);  // v_pk_fma_f32
            d = __builtin_elementwise_fma(xy[k], yy, d);
            d = __builtin_elementwise_fma(xz[k], yz, d);
            mn[k] = fminf(fminf(d.x, d.y), mn[k]);             // v_min3_f32
        }
    }

    int* om = mins + (dir ? NPTOT : 0) + (size_t)b * NPTS
            + (size_t)xtile * (NTHR * XR);
#pragma unroll
    for (int k = 0; k < XR; k++) {
        atomicMin(&om[k * NTHR + t], f2key(mn[k]));
    }
}

__global__ __launch_bounds__(NTHR) void reduce1(
        const int* __restrict__ mins, const float* __restrict__ Sw,
        float2* __restrict__ part) {
    __shared__ float s1[NTHR], s2[NTHR];
    int t = threadIdx.x;
    float sx = 0.f, sy = 0.f;
    for (int i = blockIdx.x * NTHR + t; i < NPTOT; i += RBLK * NTHR) {
        sx += key2f(mins[i]) + Sw[i];                    // min + ||x||^2
        sy += key2f(mins[NPTOT + i]) + Sw[NPTOT + i];    // min + ||y||^2
    }
    s1[t] = sx; s2[t] = sy;
    __syncthreads();
    for (int s = NTHR / 2; s > 0; s >>= 1) {
        if (t < s) { s1[t] += s1[t + s]; s2[t] += s2[t + s]; }
        __syncthreads();
    }
    if (t == 0) part[blockIdx.x] = make_float2(s1[0], s2[0]);
}

__global__ __launch_bounds__(64) void reduce2(
        const float2* __restrict__ part,
        const float* __restrict__ bpp, const float* __restrict__ lam,
        float* __restrict__ out) {
    int t = threadIdx.x;           // one wave of 64
    float2 p = part[t];
    float v = p.x + p.y;
    for (int s = 32; s > 0; s >>= 1) v += __shfl_down(v, s, 64);
    if (t == 0) {
        const float inv = 1.0f / (float)NPTOT;
        out[0] = v * inv + lam[0] * bpp[0];
    }
}

extern "C" void kernel_launch(void* const* d_in, const int* in_sizes, int n_in,
                              void* d_out, int out_size, void* d_ws, size_t ws_size,
                              hipStream_t stream) {
    const float* X   = (const float*)d_in[0];   // pc_pred  [4,8192,3]
    const float* Y   = (const float*)d_in[1];   // pc_target[4,8192,3]
    const float* bpp = (const float*)d_in[2];
    const float* lam = (const float*)d_in[3];
    float* out = (float*)d_out;

    char* w = (char*)d_ws;
    int*    mins = (int*)w;                     w += 2 * NPTOT * sizeof(int);
    float*  Sx   = (float*)w;                   w += 2 * NPTOT * sizeof(float);
    float*  Sy   = (float*)w;                   w += 2 * NPTOT * sizeof(float);
    float*  Sz   = (float*)w;                   w += 2 * NPTOT * sizeof(float);
    float*  Sw   = (float*)w;                   w += 2 * NPTOT * sizeof(float);
    float2* part = (float2*)w;

    prep<<<(2 * NPTOT + NTHR - 1) / NTHR, NTHR, 0, stream>>>(X, Y, Sx, Sy, Sz, Sw, mins);
    chamfer_pass<<<2 * NB * XTILES * YCHUNKS, NTHR, 0, stream>>>(Sx, Sy, Sz, Sw, mins);
    reduce1<<<RBLK, NTHR, 0, stream>>>(mins, Sw, part);
    reduce2<<<1, 64, 0, stream>>>(part, bpp, lam, out);
}

// Round 5
// 49.659 us; speedup vs baseline: 2.0070x; 1.0879x over previous
//
#include <hip/hip_runtime.h>

// Chamfer loss: B=4, N=M=8192, D=3, fp32 in, scalar fp32 out.
// loss = mean_n min_m ||x_n-y_m||^2 + mean_m min_n ||...||^2 + lambda*bpp
//
// R4: pass time was pinned ~45us across R1-R3 while VALU ops/pair fell
// 7->2: not issue-bound. Suspects: LDS latency exposed per iteration
// (~150cy stall vs 64cy compute) + 2M global atomicMin tail (8MB RMW).
// Fixes: (1) 128-thr blocks x 2048 (8 blocks/CU -> 16 waves/CU); y
// consumed in register groups of 4 points (4x ds_read_b128) with an
// explicit A/B software pipeline so each group's loads are in flight
// under the previous group's 64 VALU ops. (2) partial mins are plain
// coalesced stores per (dir,ychunk) - no atomics, no init kernel -
// reduced by a 2-stage tree (atomic fallback if ws too small).
// Inner loop stays packed: v_pk_fma_f32, 2 issue slots/pair.

typedef float v2f __attribute__((ext_vector_type(2)));
typedef float v4f __attribute__((ext_vector_type(4)));

#define NPTS    8192
#define NB      4
#define NPTOT   (NB * NPTS)         // 32768 points per cloud
#define NTHR    128
#define XR      8                   // x points per thread
#define XPB     (NTHR * XR)         // 1024 x per block
#define XTILES  (NPTS / XPB)        // 8
#define YC      256                 // y chunk staged in LDS
#define YCHUNKS (NPTS / YC)         // 32
#define GRID    (2 * NB * XTILES * YCHUNKS)   // 2048
#define RBLK    128                 // reduce stage-1 blocks

__device__ __forceinline__ int f2key(float f) {
    int i = __float_as_int(f);
    return i >= 0 ? i : (i ^ 0x7FFFFFFF);
}
__device__ __forceinline__ float key2f(int k) {
    return __int_as_float(k >= 0 ? k : (k ^ 0x7FFFFFFF));
}

__global__ __launch_bounds__(256) void init_min(int* mins) {
    int i = blockIdx.x * 256 + threadIdx.x;
    if (i < 2 * NPTOT) mins[i] = 0x7F800000;
}

#define LOADG(G, g)                                   \
    G##x = *(const v4f*)&lyx[4 * (g)];                \
    G##y = *(const v4f*)&lyy[4 * (g)];                \
    G##z = *(const v4f*)&lyz[4 * (g)];                \
    G##w = *(const v4f*)&lyw[4 * (g)];

#define PAIRSTEP(yx, yy, yz, yw)                                   \
    {                                                              \
        v2f _yx = (yx), _yy = (yy), _yz = (yz), _yw = (yw);        \
        _Pragma("unroll")                                          \
        for (int k = 0; k < XR; k++) {                             \
            v2f d = __builtin_elementwise_fma(xs[k], _yx, _yw);    \
            d = __builtin_elementwise_fma(ys[k], _yy, d);          \
            d = __builtin_elementwise_fma(zs[k], _yz, d);          \
            mn[k] = fminf(fminf(d.x, d.y), mn[k]);                 \
        }                                                          \
    }

#define COMPUTEG(G)                                                      \
    PAIRSTEP(__builtin_shufflevector(G##x, G##x, 0, 1),                  \
             __builtin_shufflevector(G##y, G##y, 0, 1),                  \
             __builtin_shufflevector(G##z, G##z, 0, 1),                  \
             __builtin_shufflevector(G##w, G##w, 0, 1))                  \
    PAIRSTEP(__builtin_shufflevector(G##x, G##x, 2, 3),                  \
             __builtin_shufflevector(G##y, G##y, 2, 3),                  \
             __builtin_shufflevector(G##z, G##z, 2, 3),                  \
             __builtin_shufflevector(G##w, G##w, 2, 3))

template <bool USE_ATOMIC>
__global__ __launch_bounds__(NTHR) void chamfer_pass(
        const float* __restrict__ X, const float* __restrict__ Y,
        float* __restrict__ part, int* __restrict__ mins) {
    // grid = 2048: dir(2) x batch(4) x xtile(8) x ychunk(32)
    int bid = blockIdx.x;
    int dir = bid >> 10;
    int r   = bid & 1023;
    int b   = r >> 8;
    int rem = r & 255;
    int xt  = rem >> 5;
    int yc  = rem & 31;

    const float* src   = dir ? Y : X;   // cloud we take mins FOR
    const float* other = dir ? X : Y;   // cloud we min OVER

    __shared__ __align__(16) float lyx[YC], lyy[YC], lyz[YC], lyw[YC];
    int t = threadIdx.x;

    // stage 2 y-points per thread from raw interleaved xyz; SoA in LDS
    {
        const float* yb = other + ((size_t)b * NPTS + (size_t)yc * YC + 2 * t) * 3;
        float ax = yb[0], ay = yb[1], az = yb[2];
        float bx = yb[3], by = yb[4], bz = yb[5];
        *(float2*)&lyx[2 * t] = make_float2(ax, bx);
        *(float2*)&lyy[2 * t] = make_float2(ay, by);
        *(float2*)&lyz[2 * t] = make_float2(az, bz);
        *(float2*)&lyw[2 * t] = make_float2(
            __fmaf_rn(ax, ax, __fmaf_rn(ay, ay, az * az)),
            __fmaf_rn(bx, bx, __fmaf_rn(by, by, bz * bz)));
    }
    __syncthreads();

    // XR x-points in regs, pre-scaled by -2, splatted for pk_fma
    v2f xs[XR], ys[XR], zs[XR];
    float mn[XR];
    const float* xb = src + ((size_t)b * NPTS + (size_t)xt * XPB) * 3;
#pragma unroll
    for (int k = 0; k < XR; k++) {
        int xi = k * NTHR + t;
        float a = -2.0f * xb[3 * xi + 0];
        float bb = -2.0f * xb[3 * xi + 1];
        float c = -2.0f * xb[3 * xi + 2];
        xs[k] = (v2f){a, a};
        ys[k] = (v2f){bb, bb};
        zs[k] = (v2f){c, c};
        mn[k] = 3.0e38f;
    }

    // 64 register-groups of 4 y-points, A/B software pipeline
    v4f Ax, Ay, Az, Aw, Bx, By, Bz, Bw;
    LOADG(A, 0);
    for (int g = 0; g < (YC / 4 - 2); g += 2) {
        LOADG(B, g + 1);
        COMPUTEG(A);
        LOADG(A, g + 2);
        COMPUTEG(B);
    }
    LOADG(B, YC / 4 - 1);
    COMPUTEG(A);
    COMPUTEG(B);

    if (USE_ATOMIC) {
        int* om = mins + (dir ? NPTOT : 0) + (size_t)b * NPTS + (size_t)xt * XPB;
#pragma unroll
        for (int k = 0; k < XR; k++)
            atomicMin(&om[k * NTHR + t], f2key(mn[k]));
    } else {
        float* op = part + ((size_t)(dir * YCHUNKS + yc)) * NPTOT
                  + (size_t)b * NPTS + (size_t)xt * XPB;
#pragma unroll
        for (int k = 0; k < XR; k++)
            op[k * NTHR + t] = mn[k];
    }
}

template <bool USE_ATOMIC>
__global__ __launch_bounds__(256) void reduce1(
        const float* __restrict__ part, const int* __restrict__ mins,
        const float* __restrict__ X, const float* __restrict__ Y,
        float2* __restrict__ out2) {
    __shared__ float s1[256], s2[256];
    int t = threadIdx.x;
    float sx = 0.f, sy = 0.f;
    for (int i = blockIdx.x * 256 + t; i < NPTOT; i += RBLK * 256) {
        float mx, my;
        if (USE_ATOMIC) {
            mx = key2f(mins[i]);
            my = key2f(mins[NPTOT + i]);
        } else {
            mx = 3.0e38f; my = 3.0e38f;
#pragma unroll
            for (int c = 0; c < YCHUNKS; c++) {
                mx = fminf(mx, part[(size_t)c * NPTOT + i]);
                my = fminf(my, part[(size_t)(YCHUNKS + c) * NPTOT + i]);
            }
        }
        float a = X[3 * i], bb = X[3 * i + 1], c = X[3 * i + 2];
        sx += mx + __fmaf_rn(a, a, __fmaf_rn(bb, bb, c * c));
        float d = Y[3 * i], e = Y[3 * i + 1], f = Y[3 * i + 2];
        sy += my + __fmaf_rn(d, d, __fmaf_rn(e, e, f * f));
    }
    s1[t] = sx; s2[t] = sy;
    __syncthreads();
    for (int s = 128; s > 0; s >>= 1) {
        if (t < s) { s1[t] += s1[t + s]; s2[t] += s2[t + s]; }
        __syncthreads();
    }
    if (t == 0) out2[blockIdx.x] = make_float2(s1[0], s2[0]);
}

__global__ __launch_bounds__(RBLK) void reduce2(
        const float2* __restrict__ p2,
        const float* __restrict__ bpp, const float* __restrict__ lam,
        float* __restrict__ out) {
    __shared__ float s[RBLK];
    int t = threadIdx.x;
    float2 p = p2[t];
    s[t] = p.x + p.y;
    __syncthreads();
    for (int h = RBLK / 2; h > 0; h >>= 1) {
        if (t < h) s[t] += s[t + h];
        __syncthreads();
    }
    if (t == 0) out[0] = s[0] * (1.0f / (float)NPTOT) + lam[0] * bpp[0];
}

extern "C" void kernel_launch(void* const* d_in, const int* in_sizes, int n_in,
                              void* d_out, int out_size, void* d_ws, size_t ws_size,
                              hipStream_t stream) {
    const float* X   = (const float*)d_in[0];   // pc_pred  [4,8192,3]
    const float* Y   = (const float*)d_in[1];   // pc_target[4,8192,3]
    const float* bpp = (const float*)d_in[2];
    const float* lam = (const float*)d_in[3];
    float* out = (float*)d_out;

    char* w = (char*)d_ws;
    float2* p2 = (float2*)w;            // RBLK float2 partials (1 KB)
    char* w2 = w + 1024;

    size_t need_store = (size_t)2 * YCHUNKS * NPTOT * sizeof(float);  // 8 MB
    bool use_atomic = (ws_size < 1024 + need_store);

    if (use_atomic) {
        int* mins = (int*)w2;
        init_min<<<(2 * NPTOT + 255) / 256, 256, 0, stream>>>(mins);
        chamfer_pass<true><<<GRID, NTHR, 0, stream>>>(X, Y, nullptr, mins);
        reduce1<true><<<RBLK, 256, 0, stream>>>(nullptr, mins, X, Y, p2);
    } else {
        float* part = (float*)w2;
        chamfer_pass<false><<<GRID, NTHR, 0, stream>>>(X, Y, part, nullptr);
        reduce1<false><<<RBLK, 256, 0, stream>>>(part, nullptr, X, Y, p2);
    }
    reduce2<<<1, RBLK, 0, stream>>>(p2, bpp, lam, out);
}